// Round 14
// baseline (233.013 us; speedup 1.0000x reference)
//
#include <hip/hip_runtime.h>
#include <math.h>

#define N 50000
#define E 800000
#define KCHEB 10
#define BT 20
#define N64 ((size_t)N * 64)
#define UROW ((size_t)(N + 1) * 64)    // u-arrays have a zeroed pad row N
#define CONV_BLOCKS 1563               // ceil((N64/8)/256)
#define NB 196                         // row buckets (256 rows each)
#define EPB 2048                       // edges per bucket-sort block
#define ABLK ((E + EPB - 1) / EPB)     // 391
#define BCAP 5120                      // bucket capacity (mean 4082, +16 sigma)
#define PHASE_GRID 2048                // 8 blocks/CU co-resident (launch_bounds 256,8)
#define NGROUP 3125                    // N/16 row-groups

typedef __attribute__((ext_vector_type(8))) short short8;   // 8 bf16 = 4 VGPRs
typedef __attribute__((ext_vector_type(4))) float f32x4;    // MFMA acc

// ---- bf16 helpers (manual, RNE) ----
__device__ __forceinline__ unsigned f2bf(float x) {
    unsigned u = __float_as_uint(x);
    return (u + 0x7FFFu + ((u >> 16) & 1u)) >> 16;
}
__device__ __forceinline__ float bf2f(unsigned h) {
    return __uint_as_float(h << 16);
}
__device__ __forceinline__ unsigned packbf(float lo, float hi) {
    return f2bf(lo) | (f2bf(hi) << 16);
}
__device__ __forceinline__ void unpack8(uint4 v, float* f) {
    f[0]=bf2f(v.x&0xFFFFu); f[1]=bf2f(v.x>>16);
    f[2]=bf2f(v.y&0xFFFFu); f[3]=bf2f(v.y>>16);
    f[4]=bf2f(v.z&0xFFFFu); f[5]=bf2f(v.z>>16);
    f[6]=bf2f(v.w&0xFFFFu); f[7]=bf2f(v.w>>16);
}
__device__ __forceinline__ uint4 pack8(const float* f) {
    return make_uint4(packbf(f[0],f[1]),packbf(f[2],f[3]),packbf(f[4],f[5]),packbf(f[6],f[7]));
}

// ---- W pack helper: [Wtop;Wbot] (128 x ncols) -> MFMA B-frags ----
__device__ __forceinline__ void pack_one(const float* Wtop, const float* Wbot,
                                         int ncols, uint4* out, int id) {
    int ntiles = ncols >> 4;
    int lane = id & 63;
    int nt = (id >> 6) % ntiles;
    int kt = id / (64 * ntiles);
    int n = nt * 16 + (lane & 15);
    int k0 = kt * 32 + (lane >> 4) * 8;
    const float* src = (k0 < 64) ? (Wtop + k0 * ncols + n) : (Wbot + (k0 - 64) * ncols + n);
    unsigned r[4];
#pragma unroll
    for (int p = 0; p < 4; p++)
        r[p] = packbf(src[(2 * p) * ncols], src[(2 * p + 1) * ncols]);
    out[id] = make_uint4(r[0], r[1], r[2], r[3]);
}

// ---------------- K1: edge bucket-sort (LDS counting sort) + x->bf16 + W packs --
__global__ __launch_bounds__(256) void k1_bucket_conv_pack(
        const int* __restrict__ row, const int* __restrict__ col,
        int* __restrict__ btail, int2* __restrict__ bucketArr,
        const float4* __restrict__ xin, uint4* __restrict__ xbf,
        const float* __restrict__ Wd, const float* __restrict__ Wh1,
        const float* __restrict__ Whd, const float* __restrict__ Wh2,
        uint4* __restrict__ Wfrag1, uint4* __restrict__ Wfrag2) {
    int b = blockIdx.x, tid = threadIdx.x;
    if (b < ABLK) {
        __shared__ int2 buf[EPB];         // 16 KB staging
        __shared__ int cnt[256];
        __shared__ int offs[256];
        __shared__ int gb[256];
        int base = b * EPB;
        int n = E - base; if (n > EPB) n = EPB;
        int r[8], c[8], p[8];
        cnt[tid] = 0;
        __syncthreads();
#pragma unroll
        for (int j = 0; j < 8; j++) {
            int e = base + j * 256 + tid;
            if (e < base + n) {
                r[j] = row[e]; c[j] = col[e];
                p[j] = atomicAdd(&cnt[r[j] >> 8], 1);
            } else r[j] = -1;
        }
        __syncthreads();
        offs[tid] = cnt[tid];
        __syncthreads();
        for (int o = 1; o < 256; o <<= 1) {
            int u = (tid >= o) ? offs[tid - o] : 0;
            __syncthreads();
            offs[tid] += u;
            __syncthreads();
        }
        int excl = offs[tid] - cnt[tid];
        __syncthreads();
        offs[tid] = excl;
        if (tid < NB && cnt[tid] > 0) gb[tid] = atomicAdd(&btail[tid], cnt[tid]);
        __syncthreads();
#pragma unroll
        for (int j = 0; j < 8; j++)
            if (r[j] >= 0) buf[offs[r[j] >> 8] + p[j]] = make_int2(r[j], c[j]);
        __syncthreads();
        for (int i = tid; i < n; i += 256) {
            int2 eg = buf[i];
            int bb = eg.x >> 8;
            int pos = gb[bb] + (i - offs[bb]);
            if (pos < BCAP) bucketArr[(size_t)bb * BCAP + pos] = eg;
        }
    } else if (b < ABLK + CONV_BLOCKS) {
        int i = (b - ABLK) * 256 + tid;
        if (i < (int)(N64 / 8)) {
            float4 a = xin[2 * i], c = xin[2 * i + 1];
            uint4 o;
            o.x = packbf(a.x, a.y); o.y = packbf(a.z, a.w);
            o.z = packbf(c.x, c.y); o.w = packbf(c.z, c.w);
            xbf[i] = o;
        }
    } else if (b < ABLK + CONV_BLOCKS + 4) {
        int id = (b - ABLK - CONV_BLOCKS) * 256 + tid;
        if (id < 1024) pack_one(Wd, Wh1, 64, Wfrag1, id);
    } else {
        int id = (b - ABLK - CONV_BLOCKS - 4) * 256 + tid;
        if (id < 512) pack_one(Whd, Wh2, 32, Wfrag2, id);
    }
}

// ---------------- K_ELL fused: bucket -> ELL + deg/dinv/pad/xu + coeffs --------
// Blocks [0,NB): one per bucket. LDS row counters -> ELL; then per-row deg,
// dinv, ELL pad-to-8 (offset N<<7 -> zero row), and xu = bf16(dinv .* x), all
// from LDS (no global deg round-trip). Block NB: coeffs/kmax + zero pad rows.
__global__ __launch_bounds__(256) void k_ell_fused(
        const int2* __restrict__ bucketArr, const int* __restrict__ btail,
        int* __restrict__ ell, int* __restrict__ deg,
        const float* __restrict__ x, float* __restrict__ dinv,
        unsigned short* __restrict__ xu, unsigned short* __restrict__ Uarr,
        unsigned short* __restrict__ hidu, int nslots,
        const float* __restrict__ tptr, float* __restrict__ coeffs,
        int* __restrict__ kmaxp) {
    int b = blockIdx.x, tid = threadIdx.x;
    if (b < NB) {
        __shared__ int rcnt[256];
        __shared__ float sdr[256];
        rcnt[tid] = 0;
        __syncthreads();
        int cnt = btail[b]; if (cnt > BCAP) cnt = BCAP;
        const int2* src = bucketArr + (size_t)b * BCAP;
        for (int i = tid; i < cnt; i += 256) {
            int2 eg = src[i];
            int s = atomicAdd(&rcnt[eg.x & 255], 1);
            if (s < 64) ell[(size_t)eg.x * 64 + s] = eg.y << 7;   // byte offset c*128
        }
        __syncthreads();
        int r0 = b << 8;
        int rr = r0 + tid;
        int dc = rcnt[tid];
        int d = dc > 64 ? 64 : dc;
        float dr = (d > 0) ? rsqrtf((float)d) : 0.f;
        sdr[tid] = dr;
        if (rr < N) {
            deg[rr] = dc;
            dinv[rr] = dr;
            int dpad = (d + 7) & ~7;
            for (int j = d; j < dpad; j++) ell[(size_t)rr * 64 + j] = (N << 7);
        }
        __syncthreads();
        for (int u = tid; u < 2048; u += 256) {      // 256 rows x 8 uint4
            int lr = u >> 3, sub = u & 7;
            int r = r0 + lr;
            if (r < N) {
                float drr = sdr[lr];
                const float* xp = x + (size_t)r * 64 + sub * 8;
                float4 a = *(const float4*)xp, c = *(const float4*)(xp + 4);
                float f[8] = {drr*a.x, drr*a.y, drr*a.z, drr*a.w,
                              drr*c.x, drr*c.y, drr*c.z, drr*c.w};
                ((uint4*)xu)[(size_t)r * 8 + sub] = pack8(f);
            }
        }
    } else {
        // coeffs + kmax (bf16-ulp cutoff: terms below leading term's bf16
        // rounding noise are indistinguishable from quantization) + pad rows
        __shared__ float sc[KCHEB];
        int v = tid;
        if (v < KCHEB) {
            float tt = tptr[0];
            float lt = logf(0.5f * tt);
            float s = 0.f;
            for (int m = 0; m < BT; m++) {
                float lg = lgammaf((float)m + 1.0f) + lgammaf((float)(m + v) + 1.0f);
                s += expf((2.0f * m + (float)v) * lt - lg);
            }
            float c;
            if (v == 0) c = s;
            else c = ((v & 1) == 0) ? 2.0f * s : -2.0f * s;
            coeffs[v] = c;
            sc[v] = c;
        }
        __syncthreads();
        if (v == 0) {
            float c0 = fabsf(sc[0]);
            int kmax = 1;
            for (int k = 1; k < KCHEB; k++)
                if (fabsf(sc[k]) >= 0.00390625f * c0) kmax = k;   // bf16 ulp cutoff
            kmaxp[0] = kmax;
        }
        // zero pad rows: xu row N, nslots U rows, hidu row (8 uint4 each)
        int total = (nslots + 2) * 8;
        if (tid < total) {
            int which = tid >> 3, q = tid & 7;
            uint4* dst;
            if (which == 0)           dst = (uint4*)(xu + (size_t)N * 64);
            else if (which <= nslots) dst = (uint4*)(Uarr + (size_t)(which - 1) * UROW + (size_t)N * 64);
            else                      dst = (uint4*)(hidu + (size_t)N * 64);
            dst[q] = make_uint4(0, 0, 0, 0);
        }
    }
}

// ---------------- persistent SpMM phase: loops k=1..kmax, NORMAL launch --------
// R8/R13 established: cooperative launch MODE kills gather speed; normal-launch
// persistent shape is fine. Grid 2048 = 8 blocks/CU co-resident by capacity
// (launch_bounds(256,8) caps VGPR<=64; spmm needs ~32, no LDS) -> restores
// R12's 32-waves/CU gather concurrency. Generation-counter spin barrier
// (agent scope) between consecutive LIVE steps only; at kmax==1 it never runs.
__global__ __launch_bounds__(256, 8) void spmm_phase(
        const int* __restrict__ deg, const int* __restrict__ ell,
        const unsigned short* __restrict__ baseu, const unsigned short* __restrict__ baseT,
        unsigned short* __restrict__ Tarr, unsigned short* __restrict__ Uarr,
        int nslots, const float* __restrict__ dinv,
        const int* __restrict__ kmaxp, int* __restrict__ barcnt) {
    int tid = threadIdx.x;
    int lane = tid & 63;
    int lane8 = lane & 7;
    int gbase = lane & 56;
    int h = (lane >> 3) & 1;
    int myoff16 = lane8 * 16;
    int kmax = kmaxp[0]; if (kmax > KCHEB - 1) kmax = KCHEB - 1;
    for (int k = 1; k <= kmax; k++) {
        const unsigned short* uin = (k == 1) ? baseu
                                  : Uarr + (size_t)((k - 2) % nslots) * UROW;
        const uint4* tkm2 = (const uint4*)((k <= 2) ? baseT
                                  : Tarr + (size_t)((k - 3) % nslots) * N64);
        uint4* Tout = (uint4*)(Tarr + (size_t)((k - 1) % nslots) * N64);
        uint4* Uout = (uint4*)(Uarr + (size_t)((k - 1) % nslots) * UROW);
        const char* vbase = (const char*)uin;
        for (int rb = blockIdx.x; rb < NGROUP; rb += PHASE_GRID) {
            int r = rb * 16 + (tid >> 6) * 4 + (lane >> 4);
            int d = deg[r]; if (d > 64) d = 64;
            int dpad = (d + 7) & ~7;
            const int* erow = ell + (size_t)r * 64;
            float a0=0,a1=0,a2=0,a3=0,a4=0,a5=0,a6=0,a7=0;
            for (int j0 = h * 8; j0 < dpad; j0 += 16) {
                int myoff = erow[j0 + lane8];     // pads -> row N (zeros)
#pragma unroll
                for (int i = 0; i < 8; i++) {
                    int off = __shfl(myoff, gbase + i, 64);
                    uint4 v = *(const uint4*)(vbase + off + myoff16);
                    a0 += bf2f(v.x & 0xFFFFu);
                    a1 += bf2f(v.x >> 16);
                    a2 += bf2f(v.y & 0xFFFFu);
                    a3 += bf2f(v.y >> 16);
                    a4 += bf2f(v.z & 0xFFFFu);
                    a5 += bf2f(v.z >> 16);
                    a6 += bf2f(v.w & 0xFFFFu);
                    a7 += bf2f(v.w >> 16);
                }
            }
            a0 += __shfl_xor(a0, 8, 64);
            a1 += __shfl_xor(a1, 8, 64);
            a2 += __shfl_xor(a2, 8, 64);
            a3 += __shfl_xor(a3, 8, 64);
            a4 += __shfl_xor(a4, 8, 64);
            a5 += __shfl_xor(a5, 8, 64);
            a6 += __shfl_xor(a6, 8, 64);
            a7 += __shfl_xor(a7, 8, 64);
            if (h == 0) {
                float dr = dinv[r];
                float ndr = -dr;
                float s0=ndr*a0, s1=ndr*a1, s2=ndr*a2, s3=ndr*a3;
                float s4=ndr*a4, s5=ndr*a5, s6=ndr*a6, s7=ndr*a7;
                int idx = r * 8 + lane8;
                if (k >= 2) {
                    uint4 tm = tkm2[idx];
                    s0 = 2.f*s0 - bf2f(tm.x & 0xFFFFu);
                    s1 = 2.f*s1 - bf2f(tm.x >> 16);
                    s2 = 2.f*s2 - bf2f(tm.y & 0xFFFFu);
                    s3 = 2.f*s3 - bf2f(tm.y >> 16);
                    s4 = 2.f*s4 - bf2f(tm.z & 0xFFFFu);
                    s5 = 2.f*s5 - bf2f(tm.z >> 16);
                    s6 = 2.f*s6 - bf2f(tm.w & 0xFFFFu);
                    s7 = 2.f*s7 - bf2f(tm.w >> 16);
                }
                float t8[8] = {s0,s1,s2,s3,s4,s5,s6,s7};
                Tout[idx] = pack8(t8);
                float u8[8] = {dr*s0,dr*s1,dr*s2,dr*s3,dr*s4,dr*s5,dr*s6,dr*s7};
                Uout[idx] = pack8(u8);
            }
        }
        if (k < kmax) {
            __threadfence();
            __syncthreads();
            if (tid == 0) {
                __hip_atomic_fetch_add(barcnt, 1, __ATOMIC_ACQ_REL, __HIP_MEMORY_SCOPE_AGENT);
                int target = PHASE_GRID * k;
                while (__hip_atomic_load(barcnt, __ATOMIC_ACQUIRE, __HIP_MEMORY_SCOPE_AGENT) < target)
                    __builtin_amdgcn_s_sleep(8);
            }
            __syncthreads();
        }
    }
}

// ---------------- MFMA matmul: hidden = relu([base|heat] @ Bfrag), 64 cols ------
// Also emits hidu = bf16(dinv .* hidden) as phase-2's pre-scaled gather source.
__global__ __launch_bounds__(256) void matmul_hidden(
        const unsigned short* __restrict__ basebf, const unsigned short* __restrict__ Tarr,
        int nslots, const float* __restrict__ coeffs, const int* __restrict__ kmaxp,
        const uint4* __restrict__ Wfrag, unsigned short* __restrict__ hidbf,
        const float* __restrict__ dinv, unsigned short* __restrict__ hidu) {
    __shared__ __align__(16) unsigned short At[64][136];   // pad 8 -> row stride 272B
    int tid = threadIdx.x;
    int row0 = blockIdx.x * 64;
    int kmax = kmaxp[0]; if (kmax > KCHEB - 1) kmax = KCHEB - 1;
    float c0 = coeffs[0];
    for (int u = tid; u < 1024; u += 256) {
        int rr = u >> 4, seg = u & 15;
        int r = row0 + rr;
        uint4 val = make_uint4(0, 0, 0, 0);
        int col;
        if (seg < 8) {
            col = seg * 8;
            if (r < N) val = *(const uint4*)(basebf + (size_t)r * 64 + seg * 8);
        } else {
            int s = seg - 8;
            col = 64 + s * 8;
            if (r < N) {
                uint4 xv = *(const uint4*)(basebf + (size_t)r * 64 + s * 8);
                float h[8], f[8];
                unpack8(xv, f);
#pragma unroll
                for (int q = 0; q < 8; q++) h[q] = c0 * f[q];
                for (int j = 1; j <= kmax; j++) {
                    const unsigned short* Tj = Tarr + (size_t)((j - 1) % nslots) * N64;
                    uint4 tv = *(const uint4*)(Tj + (size_t)r * 64 + s * 8);
                    float g[8];
                    unpack8(tv, g);
                    float cj = coeffs[j];
#pragma unroll
                    for (int q = 0; q < 8; q++) h[q] = fmaf(cj, g[q], h[q]);
                }
                val = pack8(h);
            }
        }
        *(uint4*)&At[rr][col] = val;
    }
    __syncthreads();
    int wv = tid >> 6, lane = tid & 63;
    int m0 = wv * 16;
    short8 afr[4];
#pragma unroll
    for (int kt = 0; kt < 4; kt++)
        afr[kt] = *(const short8*)&At[m0 + (lane & 15)][kt * 32 + (lane >> 4) * 8];
    f32x4 acc[4];
#pragma unroll
    for (int nt = 0; nt < 4; nt++) acc[nt] = (f32x4){0.f, 0.f, 0.f, 0.f};
#pragma unroll
    for (int nt = 0; nt < 4; nt++) {
#pragma unroll
        for (int kt = 0; kt < 4; kt++) {
            short8 bfr = *(const short8*)&Wfrag[kt * 256 + nt * 64 + lane];
            acc[nt] = __builtin_amdgcn_mfma_f32_16x16x32_bf16(afr[kt], bfr, acc[nt], 0, 0, 0);
        }
    }
    float drow[4];
#pragma unroll
    for (int i = 0; i < 4; i++) {
        int r = row0 + m0 + (lane >> 4) * 4 + i;
        drow[i] = (r < N) ? dinv[r] : 0.f;
    }
#pragma unroll
    for (int nt = 0; nt < 4; nt++) {
#pragma unroll
        for (int i = 0; i < 4; i++) {
            int r = row0 + m0 + (lane >> 4) * 4 + i;
            if (r < N) {
                float hv = fmaxf(acc[nt][i], 0.f);
                size_t o = (size_t)r * 64 + nt * 16 + (lane & 15);
                hidbf[o] = (unsigned short)f2bf(hv);
                hidu[o]  = (unsigned short)f2bf(drow[i] * hv);
            }
        }
    }
}

// ---------------- MFMA matmul + log_softmax: out = lsm([hid|heat2] @ Bfrag) ----
__global__ __launch_bounds__(256) void matmul_out(
        const unsigned short* __restrict__ basebf, const unsigned short* __restrict__ Tarr,
        int nslots, const float* __restrict__ coeffs, const int* __restrict__ kmaxp,
        const uint4* __restrict__ Wfrag, float* __restrict__ out) {
    __shared__ __align__(16) unsigned short At[64][136];
    int tid = threadIdx.x;
    int row0 = blockIdx.x * 64;
    int kmax = kmaxp[0]; if (kmax > KCHEB - 1) kmax = KCHEB - 1;
    float c0 = coeffs[0];
    for (int u = tid; u < 1024; u += 256) {
        int rr = u >> 4, seg = u & 15;
        int r = row0 + rr;
        uint4 val = make_uint4(0, 0, 0, 0);
        int col;
        if (seg < 8) {
            col = seg * 8;
            if (r < N) val = *(const uint4*)(basebf + (size_t)r * 64 + seg * 8);
        } else {
            int s = seg - 8;
            col = 64 + s * 8;
            if (r < N) {
                uint4 xv = *(const uint4*)(basebf + (size_t)r * 64 + s * 8);
                float h[8], f[8];
                unpack8(xv, f);
#pragma unroll
                for (int q = 0; q < 8; q++) h[q] = c0 * f[q];
                for (int j = 1; j <= kmax; j++) {
                    const unsigned short* Tj = Tarr + (size_t)((j - 1) % nslots) * N64;
                    uint4 tv = *(const uint4*)(Tj + (size_t)r * 64 + s * 8);
                    float g[8];
                    unpack8(tv, g);
                    float cj = coeffs[j];
#pragma unroll
                    for (int q = 0; q < 8; q++) h[q] = fmaf(cj, g[q], h[q]);
                }
                val = pack8(h);
            }
        }
        *(uint4*)&At[rr][col] = val;
    }
    __syncthreads();
    int wv = tid >> 6, lane = tid & 63;
    int m0 = wv * 16;
    short8 afr[4];
#pragma unroll
    for (int kt = 0; kt < 4; kt++)
        afr[kt] = *(const short8*)&At[m0 + (lane & 15)][kt * 32 + (lane >> 4) * 8];
    f32x4 acc[2];
    acc[0] = (f32x4){0.f, 0.f, 0.f, 0.f};
    acc[1] = (f32x4){0.f, 0.f, 0.f, 0.f};
#pragma unroll
    for (int nt = 0; nt < 2; nt++) {
#pragma unroll
        for (int kt = 0; kt < 4; kt++) {
            short8 bfr = *(const short8*)&Wfrag[kt * 128 + nt * 64 + lane];
            acc[nt] = __builtin_amdgcn_mfma_f32_16x16x32_bf16(afr[kt], bfr, acc[nt], 0, 0, 0);
        }
    }
#pragma unroll
    for (int i = 0; i < 4; i++) {
        float f0 = acc[0][i], f1 = acc[1][i];
        float m = fmaxf(f0, f1);
#pragma unroll
        for (int o = 1; o < 16; o <<= 1) m = fmaxf(m, __shfl_xor(m, o, 64));
        float s = expf(f0 - m) + expf(f1 - m);
#pragma unroll
        for (int o = 1; o < 16; o <<= 1) s += __shfl_xor(s, o, 64);
        float ls = m + logf(s);
        int r = row0 + m0 + (lane >> 4) * 4 + i;
        if (r < N) {
            out[(size_t)r * 32 + (lane & 15)] = f0 - ls;
            out[(size_t)r * 32 + 16 + (lane & 15)] = f1 - ls;
        }
    }
}

extern "C" void kernel_launch(void* const* d_in, const int* in_sizes, int n_in,
                              void* d_out, int out_size, void* d_ws, size_t ws_size,
                              hipStream_t stream) {
    const float* x   = (const float*)d_in[0];
    const int*   ei  = (const int*)d_in[1];
    const float* Wd  = (const float*)d_in[2];
    const float* Wh1 = (const float*)d_in[3];
    const float* Whd = (const float*)d_in[4];
    const float* Wh2 = (const float*)d_in[5];
    const float* tp  = (const float*)d_in[6];
    const int* row = ei;
    const int* col = ei + E;

    size_t off = 0;
    auto alloc = [&](size_t bytes) -> void* {
        void* p = (char*)d_ws + off;
        off += (bytes + 255) & ~(size_t)255;
        return p;
    };
    int*   btail  = (int*)alloc((size_t)512 * 4);          // [0,NB) tails; [256],[257] barrier counters
    int*   bar1   = btail + 256;
    int*   bar2   = btail + 257;
    int*   deg    = (int*)alloc((size_t)N * 4);
    float* dinv   = (float*)alloc((size_t)N * 4);
    float* coeffs = (float*)alloc(KCHEB * 4);
    int*   kmaxp  = (int*)alloc(4);
    int*   ell    = (int*)alloc((size_t)N * 64 * 4);
    int2*  bucketArr = (int2*)alloc((size_t)NB * BCAP * 8);   // 8.0 MB
    unsigned short* xbf   = (unsigned short*)alloc(N64 * 2);
    unsigned short* xu    = (unsigned short*)alloc(UROW * 2);
    unsigned short* hidbf = (unsigned short*)alloc(N64 * 2);
    unsigned short* hidu  = (unsigned short*)alloc(UROW * 2);
    uint4* Wfrag1 = (uint4*)alloc(1024 * 16);
    uint4* Wfrag2 = (uint4*)alloc(512 * 16);
    size_t per_slot = N64 * 2 + UROW * 2 + 512;
    int nslots = (int)((ws_size - off) / per_slot);
    if (nslots > KCHEB - 1) nslots = KCHEB - 1;
    if (nslots < 3) nslots = 3;    // barrier path slot-aliasing requires >=3
    unsigned short* Tarr = (unsigned short*)alloc((size_t)nslots * N64 * 2);
    unsigned short* Uarr = (unsigned short*)alloc((size_t)nslots * UROW * 2);

    hipMemsetAsync(btail, 0, (size_t)512 * 4, stream);

    k1_bucket_conv_pack<<<ABLK + CONV_BLOCKS + 6, 256, 0, stream>>>(
        row, col, btail, bucketArr, (const float4*)x, (uint4*)xbf,
        Wd, Wh1, Whd, Wh2, Wfrag1, Wfrag2);
    k_ell_fused<<<NB + 1, 256, 0, stream>>>(
        bucketArr, btail, ell, deg, x, dinv, xu, Uarr, hidu, nslots, tp, coeffs, kmaxp);

    const int mm_grid = (N + 63) / 64;

    // ---- heat phase 1 (persistent, normal launch, internal k-loop) ----
    spmm_phase<<<PHASE_GRID, 256, 0, stream>>>(deg, ell, xu, xbf,
                                               Tarr, Uarr, nslots, dinv, kmaxp, bar1);
    matmul_hidden<<<mm_grid, 256, 0, stream>>>(xbf, Tarr, nslots, coeffs, kmaxp,
                                               Wfrag1, hidbf, dinv, hidu);

    // ---- heat phase 2 ----
    spmm_phase<<<PHASE_GRID, 256, 0, stream>>>(deg, ell, hidu, hidbf,
                                               Tarr, Uarr, nslots, dinv, kmaxp, bar2);
    matmul_out<<<mm_grid, 256, 0, stream>>>(hidbf, Tarr, nslots, coeffs, kmaxp,
                                            Wfrag2, (float*)d_out);
}

// Round 15
// 161.801 us; speedup vs baseline: 1.4401x; 1.4401x over previous
//
#include <hip/hip_runtime.h>
#include <math.h>

#define N 50000
#define E 800000
#define KCHEB 10
#define BT 20
#define N64 ((size_t)N * 64)
#define UROW ((size_t)(N + 1) * 64)    // u-arrays have a zeroed pad row N
#define CONV_BLOCKS 1563               // ceil((N64/8)/256)
#define NB 196                         // row buckets (256 rows each)
#define EPB 2048                       // edges per bucket-sort block
#define ABLK ((E + EPB - 1) / EPB)     // 391
#define BCAP 5120                      // bucket capacity (mean 4082, +16 sigma)
#define PHASE_GRID 1024                // 4 blocks/CU: R13-proven; 8/CU thrashes L2 (R14)
#define NGROUP 3125                    // N/16 row-groups

typedef __attribute__((ext_vector_type(8))) short short8;   // 8 bf16 = 4 VGPRs
typedef __attribute__((ext_vector_type(4))) float f32x4;    // MFMA acc

// ---- bf16 helpers (manual, RNE) ----
__device__ __forceinline__ unsigned f2bf(float x) {
    unsigned u = __float_as_uint(x);
    return (u + 0x7FFFu + ((u >> 16) & 1u)) >> 16;
}
__device__ __forceinline__ float bf2f(unsigned h) {
    return __uint_as_float(h << 16);
}
__device__ __forceinline__ unsigned packbf(float lo, float hi) {
    return f2bf(lo) | (f2bf(hi) << 16);
}
__device__ __forceinline__ void unpack8(uint4 v, float* f) {
    f[0]=bf2f(v.x&0xFFFFu); f[1]=bf2f(v.x>>16);
    f[2]=bf2f(v.y&0xFFFFu); f[3]=bf2f(v.y>>16);
    f[4]=bf2f(v.z&0xFFFFu); f[5]=bf2f(v.z>>16);
    f[6]=bf2f(v.w&0xFFFFu); f[7]=bf2f(v.w>>16);
}
__device__ __forceinline__ uint4 pack8(const float* f) {
    return make_uint4(packbf(f[0],f[1]),packbf(f[2],f[3]),packbf(f[4],f[5]),packbf(f[6],f[7]));
}

// ---- W pack helper: [Wtop;Wbot] (128 x ncols) -> MFMA B-frags ----
__device__ __forceinline__ void pack_one(const float* Wtop, const float* Wbot,
                                         int ncols, uint4* out, int id) {
    int ntiles = ncols >> 4;
    int lane = id & 63;
    int nt = (id >> 6) % ntiles;
    int kt = id / (64 * ntiles);
    int n = nt * 16 + (lane & 15);
    int k0 = kt * 32 + (lane >> 4) * 8;
    const float* src = (k0 < 64) ? (Wtop + k0 * ncols + n) : (Wbot + (k0 - 64) * ncols + n);
    unsigned r[4];
#pragma unroll
    for (int p = 0; p < 4; p++)
        r[p] = packbf(src[(2 * p) * ncols], src[(2 * p + 1) * ncols]);
    out[id] = make_uint4(r[0], r[1], r[2], r[3]);
}

// ---------------- K1: edge bucket-sort (LDS counting sort) + x->bf16 + W packs --
__global__ __launch_bounds__(256) void k1_bucket_conv_pack(
        const int* __restrict__ row, const int* __restrict__ col,
        int* __restrict__ btail, int2* __restrict__ bucketArr,
        const float4* __restrict__ xin, uint4* __restrict__ xbf,
        const float* __restrict__ Wd, const float* __restrict__ Wh1,
        const float* __restrict__ Whd, const float* __restrict__ Wh2,
        uint4* __restrict__ Wfrag1, uint4* __restrict__ Wfrag2) {
    int b = blockIdx.x, tid = threadIdx.x;
    if (b < ABLK) {
        __shared__ int2 buf[EPB];         // 16 KB staging
        __shared__ int cnt[256];
        __shared__ int offs[256];
        __shared__ int gb[256];
        int base = b * EPB;
        int n = E - base; if (n > EPB) n = EPB;
        int r[8], c[8], p[8];
        cnt[tid] = 0;
        __syncthreads();
#pragma unroll
        for (int j = 0; j < 8; j++) {
            int e = base + j * 256 + tid;
            if (e < base + n) {
                r[j] = row[e]; c[j] = col[e];
                p[j] = atomicAdd(&cnt[r[j] >> 8], 1);
            } else r[j] = -1;
        }
        __syncthreads();
        offs[tid] = cnt[tid];
        __syncthreads();
        for (int o = 1; o < 256; o <<= 1) {
            int u = (tid >= o) ? offs[tid - o] : 0;
            __syncthreads();
            offs[tid] += u;
            __syncthreads();
        }
        int excl = offs[tid] - cnt[tid];
        __syncthreads();
        offs[tid] = excl;
        if (tid < NB && cnt[tid] > 0) gb[tid] = atomicAdd(&btail[tid], cnt[tid]);
        __syncthreads();
#pragma unroll
        for (int j = 0; j < 8; j++)
            if (r[j] >= 0) buf[offs[r[j] >> 8] + p[j]] = make_int2(r[j], c[j]);
        __syncthreads();
        for (int i = tid; i < n; i += 256) {
            int2 eg = buf[i];
            int bb = eg.x >> 8;
            int pos = gb[bb] + (i - offs[bb]);
            if (pos < BCAP) bucketArr[(size_t)bb * BCAP + pos] = eg;
        }
    } else if (b < ABLK + CONV_BLOCKS) {
        int i = (b - ABLK) * 256 + tid;
        if (i < (int)(N64 / 8)) {
            float4 a = xin[2 * i], c = xin[2 * i + 1];
            uint4 o;
            o.x = packbf(a.x, a.y); o.y = packbf(a.z, a.w);
            o.z = packbf(c.x, c.y); o.w = packbf(c.z, c.w);
            xbf[i] = o;
        }
    } else if (b < ABLK + CONV_BLOCKS + 4) {
        int id = (b - ABLK - CONV_BLOCKS) * 256 + tid;
        if (id < 1024) pack_one(Wd, Wh1, 64, Wfrag1, id);
    } else {
        int id = (b - ABLK - CONV_BLOCKS - 4) * 256 + tid;
        if (id < 512) pack_one(Whd, Wh2, 32, Wfrag2, id);
    }
}

// ---------------- K_ELL fused: bucket -> ELL + deg/dinv/pad/xu + coeffs --------
// Blocks [0,NB): one per bucket. LDS row counters -> ELL; then per-row deg,
// dinv, ELL pad-to-8 (offset N<<7 -> zero row), and xu = bf16(dinv .* x), all
// from LDS (no global deg round-trip). Block NB: coeffs/kmax + zero pad rows.
__global__ __launch_bounds__(256) void k_ell_fused(
        const int2* __restrict__ bucketArr, const int* __restrict__ btail,
        int* __restrict__ ell, int* __restrict__ deg,
        const float* __restrict__ x, float* __restrict__ dinv,
        unsigned short* __restrict__ xu, unsigned short* __restrict__ Uarr,
        unsigned short* __restrict__ hidu, int nslots,
        const float* __restrict__ tptr, float* __restrict__ coeffs,
        int* __restrict__ kmaxp) {
    int b = blockIdx.x, tid = threadIdx.x;
    if (b < NB) {
        __shared__ int rcnt[256];
        __shared__ float sdr[256];
        rcnt[tid] = 0;
        __syncthreads();
        int cnt = btail[b]; if (cnt > BCAP) cnt = BCAP;
        const int2* src = bucketArr + (size_t)b * BCAP;
        for (int i = tid; i < cnt; i += 256) {
            int2 eg = src[i];
            int s = atomicAdd(&rcnt[eg.x & 255], 1);
            if (s < 64) ell[(size_t)eg.x * 64 + s] = eg.y << 7;   // byte offset c*128
        }
        __syncthreads();
        int r0 = b << 8;
        int rr = r0 + tid;
        int dc = rcnt[tid];
        int d = dc > 64 ? 64 : dc;
        float dr = (d > 0) ? rsqrtf((float)d) : 0.f;
        sdr[tid] = dr;
        if (rr < N) {
            deg[rr] = dc;
            dinv[rr] = dr;
            int dpad = (d + 7) & ~7;
            for (int j = d; j < dpad; j++) ell[(size_t)rr * 64 + j] = (N << 7);
        }
        __syncthreads();
        for (int u = tid; u < 2048; u += 256) {      // 256 rows x 8 uint4
            int lr = u >> 3, sub = u & 7;
            int r = r0 + lr;
            if (r < N) {
                float drr = sdr[lr];
                const float* xp = x + (size_t)r * 64 + sub * 8;
                float4 a = *(const float4*)xp, c = *(const float4*)(xp + 4);
                float f[8] = {drr*a.x, drr*a.y, drr*a.z, drr*a.w,
                              drr*c.x, drr*c.y, drr*c.z, drr*c.w};
                ((uint4*)xu)[(size_t)r * 8 + sub] = pack8(f);
            }
        }
    } else {
        // coeffs + kmax (bf16-ulp cutoff: terms below leading term's bf16
        // rounding noise are indistinguishable from quantization) + pad rows
        __shared__ float sc[KCHEB];
        int v = tid;
        if (v < KCHEB) {
            float tt = tptr[0];
            float lt = logf(0.5f * tt);
            float s = 0.f;
            for (int m = 0; m < BT; m++) {
                float lg = lgammaf((float)m + 1.0f) + lgammaf((float)(m + v) + 1.0f);
                s += expf((2.0f * m + (float)v) * lt - lg);
            }
            float c;
            if (v == 0) c = s;
            else c = ((v & 1) == 0) ? 2.0f * s : -2.0f * s;
            coeffs[v] = c;
            sc[v] = c;
        }
        __syncthreads();
        if (v == 0) {
            float c0 = fabsf(sc[0]);
            int kmax = 1;
            for (int k = 1; k < KCHEB; k++)
                if (fabsf(sc[k]) >= 0.00390625f * c0) kmax = k;   // bf16 ulp cutoff
            kmaxp[0] = kmax;
        }
        // zero pad rows: xu row N, nslots U rows, hidu row (8 uint4 each)
        int total = (nslots + 2) * 8;
        if (tid < total) {
            int which = tid >> 3, q = tid & 7;
            uint4* dst;
            if (which == 0)           dst = (uint4*)(xu + (size_t)N * 64);
            else if (which <= nslots) dst = (uint4*)(Uarr + (size_t)(which - 1) * UROW + (size_t)N * 64);
            else                      dst = (uint4*)(hidu + (size_t)N * 64);
            dst[q] = make_uint4(0, 0, 0, 0);
        }
    }
}

// ---------------- persistent SpMM phase: loops k=1..kmax, NORMAL launch --------
// R8/R13/R14 lessons: cooperative launch MODE kills gather speed (15x, R8);
// normal-launch persistent shape is fine (R13); 8 blocks/CU thrashes per-XCD
// L2 on the 6.4 MB random-gather source (R14: FETCH 92 MB, 60 us). 4 blocks/CU
// is the sweet spot. Generation-counter spin barrier (agent scope) between
// consecutive LIVE steps only; at kmax==1 it never runs.
__global__ __launch_bounds__(256, 4) void spmm_phase(
        const int* __restrict__ deg, const int* __restrict__ ell,
        const unsigned short* __restrict__ baseu, const unsigned short* __restrict__ baseT,
        unsigned short* __restrict__ Tarr, unsigned short* __restrict__ Uarr,
        int nslots, const float* __restrict__ dinv,
        const int* __restrict__ kmaxp, int* __restrict__ barcnt) {
    int tid = threadIdx.x;
    int lane = tid & 63;
    int lane8 = lane & 7;
    int gbase = lane & 56;
    int h = (lane >> 3) & 1;
    int myoff16 = lane8 * 16;
    int kmax = kmaxp[0]; if (kmax > KCHEB - 1) kmax = KCHEB - 1;
    for (int k = 1; k <= kmax; k++) {
        const unsigned short* uin = (k == 1) ? baseu
                                  : Uarr + (size_t)((k - 2) % nslots) * UROW;
        const uint4* tkm2 = (const uint4*)((k <= 2) ? baseT
                                  : Tarr + (size_t)((k - 3) % nslots) * N64);
        uint4* Tout = (uint4*)(Tarr + (size_t)((k - 1) % nslots) * N64);
        uint4* Uout = (uint4*)(Uarr + (size_t)((k - 1) % nslots) * UROW);
        const char* vbase = (const char*)uin;
        for (int rb = blockIdx.x; rb < NGROUP; rb += PHASE_GRID) {
            int r = rb * 16 + (tid >> 6) * 4 + (lane >> 4);
            int d = deg[r]; if (d > 64) d = 64;
            int dpad = (d + 7) & ~7;
            const int* erow = ell + (size_t)r * 64;
            float a0=0,a1=0,a2=0,a3=0,a4=0,a5=0,a6=0,a7=0;
            for (int j0 = h * 8; j0 < dpad; j0 += 16) {
                int myoff = erow[j0 + lane8];     // pads -> row N (zeros)
#pragma unroll
                for (int i = 0; i < 8; i++) {
                    int off = __shfl(myoff, gbase + i, 64);
                    uint4 v = *(const uint4*)(vbase + off + myoff16);
                    a0 += bf2f(v.x & 0xFFFFu);
                    a1 += bf2f(v.x >> 16);
                    a2 += bf2f(v.y & 0xFFFFu);
                    a3 += bf2f(v.y >> 16);
                    a4 += bf2f(v.z & 0xFFFFu);
                    a5 += bf2f(v.z >> 16);
                    a6 += bf2f(v.w & 0xFFFFu);
                    a7 += bf2f(v.w >> 16);
                }
            }
            a0 += __shfl_xor(a0, 8, 64);
            a1 += __shfl_xor(a1, 8, 64);
            a2 += __shfl_xor(a2, 8, 64);
            a3 += __shfl_xor(a3, 8, 64);
            a4 += __shfl_xor(a4, 8, 64);
            a5 += __shfl_xor(a5, 8, 64);
            a6 += __shfl_xor(a6, 8, 64);
            a7 += __shfl_xor(a7, 8, 64);
            if (h == 0) {
                float dr = dinv[r];
                float ndr = -dr;
                float s0=ndr*a0, s1=ndr*a1, s2=ndr*a2, s3=ndr*a3;
                float s4=ndr*a4, s5=ndr*a5, s6=ndr*a6, s7=ndr*a7;
                int idx = r * 8 + lane8;
                if (k >= 2) {
                    uint4 tm = tkm2[idx];
                    s0 = 2.f*s0 - bf2f(tm.x & 0xFFFFu);
                    s1 = 2.f*s1 - bf2f(tm.x >> 16);
                    s2 = 2.f*s2 - bf2f(tm.y & 0xFFFFu);
                    s3 = 2.f*s3 - bf2f(tm.y >> 16);
                    s4 = 2.f*s4 - bf2f(tm.z & 0xFFFFu);
                    s5 = 2.f*s5 - bf2f(tm.z >> 16);
                    s6 = 2.f*s6 - bf2f(tm.w & 0xFFFFu);
                    s7 = 2.f*s7 - bf2f(tm.w >> 16);
                }
                float t8[8] = {s0,s1,s2,s3,s4,s5,s6,s7};
                Tout[idx] = pack8(t8);
                float u8[8] = {dr*s0,dr*s1,dr*s2,dr*s3,dr*s4,dr*s5,dr*s6,dr*s7};
                Uout[idx] = pack8(u8);
            }
        }
        if (k < kmax) {
            __threadfence();
            __syncthreads();
            if (tid == 0) {
                __hip_atomic_fetch_add(barcnt, 1, __ATOMIC_ACQ_REL, __HIP_MEMORY_SCOPE_AGENT);
                int target = PHASE_GRID * k;
                while (__hip_atomic_load(barcnt, __ATOMIC_ACQUIRE, __HIP_MEMORY_SCOPE_AGENT) < target)
                    __builtin_amdgcn_s_sleep(8);
            }
            __syncthreads();
        }
    }
}

// ---------------- MFMA matmul: hidden = relu([base|heat] @ Bfrag), 64 cols ------
// Also emits hidu = bf16(dinv .* hidden) as phase-2's pre-scaled gather source.
__global__ __launch_bounds__(256) void matmul_hidden(
        const unsigned short* __restrict__ basebf, const unsigned short* __restrict__ Tarr,
        int nslots, const float* __restrict__ coeffs, const int* __restrict__ kmaxp,
        const uint4* __restrict__ Wfrag, unsigned short* __restrict__ hidbf,
        const float* __restrict__ dinv, unsigned short* __restrict__ hidu) {
    __shared__ __align__(16) unsigned short At[64][136];   // pad 8 -> row stride 272B
    int tid = threadIdx.x;
    int row0 = blockIdx.x * 64;
    int kmax = kmaxp[0]; if (kmax > KCHEB - 1) kmax = KCHEB - 1;
    float c0 = coeffs[0];
    for (int u = tid; u < 1024; u += 256) {
        int rr = u >> 4, seg = u & 15;
        int r = row0 + rr;
        uint4 val = make_uint4(0, 0, 0, 0);
        int col;
        if (seg < 8) {
            col = seg * 8;
            if (r < N) val = *(const uint4*)(basebf + (size_t)r * 64 + seg * 8);
        } else {
            int s = seg - 8;
            col = 64 + s * 8;
            if (r < N) {
                uint4 xv = *(const uint4*)(basebf + (size_t)r * 64 + s * 8);
                float h[8], f[8];
                unpack8(xv, f);
#pragma unroll
                for (int q = 0; q < 8; q++) h[q] = c0 * f[q];
                for (int j = 1; j <= kmax; j++) {
                    const unsigned short* Tj = Tarr + (size_t)((j - 1) % nslots) * N64;
                    uint4 tv = *(const uint4*)(Tj + (size_t)r * 64 + s * 8);
                    float g[8];
                    unpack8(tv, g);
                    float cj = coeffs[j];
#pragma unroll
                    for (int q = 0; q < 8; q++) h[q] = fmaf(cj, g[q], h[q]);
                }
                val = pack8(h);
            }
        }
        *(uint4*)&At[rr][col] = val;
    }
    __syncthreads();
    int wv = tid >> 6, lane = tid & 63;
    int m0 = wv * 16;
    short8 afr[4];
#pragma unroll
    for (int kt = 0; kt < 4; kt++)
        afr[kt] = *(const short8*)&At[m0 + (lane & 15)][kt * 32 + (lane >> 4) * 8];
    f32x4 acc[4];
#pragma unroll
    for (int nt = 0; nt < 4; nt++) acc[nt] = (f32x4){0.f, 0.f, 0.f, 0.f};
#pragma unroll
    for (int nt = 0; nt < 4; nt++) {
#pragma unroll
        for (int kt = 0; kt < 4; kt++) {
            short8 bfr = *(const short8*)&Wfrag[kt * 256 + nt * 64 + lane];
            acc[nt] = __builtin_amdgcn_mfma_f32_16x16x32_bf16(afr[kt], bfr, acc[nt], 0, 0, 0);
        }
    }
    float drow[4];
#pragma unroll
    for (int i = 0; i < 4; i++) {
        int r = row0 + m0 + (lane >> 4) * 4 + i;
        drow[i] = (r < N) ? dinv[r] : 0.f;
    }
#pragma unroll
    for (int nt = 0; nt < 4; nt++) {
#pragma unroll
        for (int i = 0; i < 4; i++) {
            int r = row0 + m0 + (lane >> 4) * 4 + i;
            if (r < N) {
                float hv = fmaxf(acc[nt][i], 0.f);
                size_t o = (size_t)r * 64 + nt * 16 + (lane & 15);
                hidbf[o] = (unsigned short)f2bf(hv);
                hidu[o]  = (unsigned short)f2bf(drow[i] * hv);
            }
        }
    }
}

// ---------------- MFMA matmul + log_softmax: out = lsm([hid|heat2] @ Bfrag) ----
__global__ __launch_bounds__(256) void matmul_out(
        const unsigned short* __restrict__ basebf, const unsigned short* __restrict__ Tarr,
        int nslots, const float* __restrict__ coeffs, const int* __restrict__ kmaxp,
        const uint4* __restrict__ Wfrag, float* __restrict__ out) {
    __shared__ __align__(16) unsigned short At[64][136];
    int tid = threadIdx.x;
    int row0 = blockIdx.x * 64;
    int kmax = kmaxp[0]; if (kmax > KCHEB - 1) kmax = KCHEB - 1;
    float c0 = coeffs[0];
    for (int u = tid; u < 1024; u += 256) {
        int rr = u >> 4, seg = u & 15;
        int r = row0 + rr;
        uint4 val = make_uint4(0, 0, 0, 0);
        int col;
        if (seg < 8) {
            col = seg * 8;
            if (r < N) val = *(const uint4*)(basebf + (size_t)r * 64 + seg * 8);
        } else {
            int s = seg - 8;
            col = 64 + s * 8;
            if (r < N) {
                uint4 xv = *(const uint4*)(basebf + (size_t)r * 64 + s * 8);
                float h[8], f[8];
                unpack8(xv, f);
#pragma unroll
                for (int q = 0; q < 8; q++) h[q] = c0 * f[q];
                for (int j = 1; j <= kmax; j++) {
                    const unsigned short* Tj = Tarr + (size_t)((j - 1) % nslots) * N64;
                    uint4 tv = *(const uint4*)(Tj + (size_t)r * 64 + s * 8);
                    float g[8];
                    unpack8(tv, g);
                    float cj = coeffs[j];
#pragma unroll
                    for (int q = 0; q < 8; q++) h[q] = fmaf(cj, g[q], h[q]);
                }
                val = pack8(h);
            }
        }
        *(uint4*)&At[rr][col] = val;
    }
    __syncthreads();
    int wv = tid >> 6, lane = tid & 63;
    int m0 = wv * 16;
    short8 afr[4];
#pragma unroll
    for (int kt = 0; kt < 4; kt++)
        afr[kt] = *(const short8*)&At[m0 + (lane & 15)][kt * 32 + (lane >> 4) * 8];
    f32x4 acc[2];
    acc[0] = (f32x4){0.f, 0.f, 0.f, 0.f};
    acc[1] = (f32x4){0.f, 0.f, 0.f, 0.f};
#pragma unroll
    for (int nt = 0; nt < 2; nt++) {
#pragma unroll
        for (int kt = 0; kt < 4; kt++) {
            short8 bfr = *(const short8*)&Wfrag[kt * 128 + nt * 64 + lane];
            acc[nt] = __builtin_amdgcn_mfma_f32_16x16x32_bf16(afr[kt], bfr, acc[nt], 0, 0, 0);
        }
    }
#pragma unroll
    for (int i = 0; i < 4; i++) {
        float f0 = acc[0][i], f1 = acc[1][i];
        float m = fmaxf(f0, f1);
#pragma unroll
        for (int o = 1; o < 16; o <<= 1) m = fmaxf(m, __shfl_xor(m, o, 64));
        float s = expf(f0 - m) + expf(f1 - m);
#pragma unroll
        for (int o = 1; o < 16; o <<= 1) s += __shfl_xor(s, o, 64);
        float ls = m + logf(s);
        int r = row0 + m0 + (lane >> 4) * 4 + i;
        if (r < N) {
            out[(size_t)r * 32 + (lane & 15)] = f0 - ls;
            out[(size_t)r * 32 + 16 + (lane & 15)] = f1 - ls;
        }
    }
}

extern "C" void kernel_launch(void* const* d_in, const int* in_sizes, int n_in,
                              void* d_out, int out_size, void* d_ws, size_t ws_size,
                              hipStream_t stream) {
    const float* x   = (const float*)d_in[0];
    const int*   ei  = (const int*)d_in[1];
    const float* Wd  = (const float*)d_in[2];
    const float* Wh1 = (const float*)d_in[3];
    const float* Whd = (const float*)d_in[4];
    const float* Wh2 = (const float*)d_in[5];
    const float* tp  = (const float*)d_in[6];
    const int* row = ei;
    const int* col = ei + E;

    size_t off = 0;
    auto alloc = [&](size_t bytes) -> void* {
        void* p = (char*)d_ws + off;
        off += (bytes + 255) & ~(size_t)255;
        return p;
    };
    int*   btail  = (int*)alloc((size_t)512 * 4);          // [0,NB) tails; [256],[257] barrier counters
    int*   bar1   = btail + 256;
    int*   bar2   = btail + 257;
    int*   deg    = (int*)alloc((size_t)N * 4);
    float* dinv   = (float*)alloc((size_t)N * 4);
    float* coeffs = (float*)alloc(KCHEB * 4);
    int*   kmaxp  = (int*)alloc(4);
    int*   ell    = (int*)alloc((size_t)N * 64 * 4);
    int2*  bucketArr = (int2*)alloc((size_t)NB * BCAP * 8);   // 8.0 MB
    unsigned short* xbf   = (unsigned short*)alloc(N64 * 2);
    unsigned short* xu    = (unsigned short*)alloc(UROW * 2);
    unsigned short* hidbf = (unsigned short*)alloc(N64 * 2);
    unsigned short* hidu  = (unsigned short*)alloc(UROW * 2);
    uint4* Wfrag1 = (uint4*)alloc(1024 * 16);
    uint4* Wfrag2 = (uint4*)alloc(512 * 16);
    size_t per_slot = N64 * 2 + UROW * 2 + 512;
    int nslots = (int)((ws_size - off) / per_slot);
    if (nslots > KCHEB - 1) nslots = KCHEB - 1;
    if (nslots < 3) nslots = 3;    // barrier path slot-aliasing requires >=3
    unsigned short* Tarr = (unsigned short*)alloc((size_t)nslots * N64 * 2);
    unsigned short* Uarr = (unsigned short*)alloc((size_t)nslots * UROW * 2);

    hipMemsetAsync(btail, 0, (size_t)512 * 4, stream);

    k1_bucket_conv_pack<<<ABLK + CONV_BLOCKS + 6, 256, 0, stream>>>(
        row, col, btail, bucketArr, (const float4*)x, (uint4*)xbf,
        Wd, Wh1, Whd, Wh2, Wfrag1, Wfrag2);
    k_ell_fused<<<NB + 1, 256, 0, stream>>>(
        bucketArr, btail, ell, deg, x, dinv, xu, Uarr, hidu, nslots, tp, coeffs, kmaxp);

    const int mm_grid = (N + 63) / 64;

    // ---- heat phase 1 (persistent, normal launch, internal k-loop) ----
    spmm_phase<<<PHASE_GRID, 256, 0, stream>>>(deg, ell, xu, xbf,
                                               Tarr, Uarr, nslots, dinv, kmaxp, bar1);
    matmul_hidden<<<mm_grid, 256, 0, stream>>>(xbf, Tarr, nslots, coeffs, kmaxp,
                                               Wfrag1, hidbf, dinv, hidu);

    // ---- heat phase 2 ----
    spmm_phase<<<PHASE_GRID, 256, 0, stream>>>(deg, ell, hidu, hidbf,
                                               Tarr, Uarr, nslots, dinv, kmaxp, bar2);
    matmul_out<<<mm_grid, 256, 0, stream>>>(hidbf, Tarr, nslots, coeffs, kmaxp,
                                            Wfrag2, (float*)d_out);
}

// Round 16
// 154.333 us; speedup vs baseline: 1.5098x; 1.0484x over previous
//
#include <hip/hip_runtime.h>
#include <math.h>

#define N 50000
#define E 800000
#define KCHEB 10
#define BT 20
#define N64 ((size_t)N * 64)
#define UROWB ((size_t)(N + 1) * 64)   // fp8 u-array bytes (64 B/row, zeroed pad row N)
#define CONV_BLOCKS 1563               // ceil((N64/8)/256)
#define NB 196                         // row buckets (256 rows each)
#define EPB 2048                       // edges per bucket-sort block
#define ABLK ((E + EPB - 1) / EPB)     // 391
#define BCAP 5120                      // bucket capacity (mean 4082, +16 sigma)
#define PHASE_GRID 1024                // 4 blocks/CU: R13/R15-proven; 8/CU thrashes L2 (R14)
#define NGROUP 3125                    // N/16 row-groups

typedef __attribute__((ext_vector_type(8))) short short8;   // 8 bf16 = 4 VGPRs
typedef __attribute__((ext_vector_type(4))) float f32x4;    // MFMA acc
typedef __attribute__((ext_vector_type(2))) float f32x2;    // fp8 cvt pair

// ---- bf16 helpers (manual, RNE) ----
__device__ __forceinline__ unsigned f2bf(float x) {
    unsigned u = __float_as_uint(x);
    return (u + 0x7FFFu + ((u >> 16) & 1u)) >> 16;
}
__device__ __forceinline__ float bf2f(unsigned h) {
    return __uint_as_float(h << 16);
}
__device__ __forceinline__ unsigned packbf(float lo, float hi) {
    return f2bf(lo) | (f2bf(hi) << 16);
}
__device__ __forceinline__ void unpack8(uint4 v, float* f) {
    f[0]=bf2f(v.x&0xFFFFu); f[1]=bf2f(v.x>>16);
    f[2]=bf2f(v.y&0xFFFFu); f[3]=bf2f(v.y>>16);
    f[4]=bf2f(v.z&0xFFFFu); f[5]=bf2f(v.z>>16);
    f[6]=bf2f(v.w&0xFFFFu); f[7]=bf2f(v.w>>16);
}
__device__ __forceinline__ uint4 pack8(const float* f) {
    return make_uint4(packbf(f[0],f[1]),packbf(f[2],f[3]),packbf(f[4],f[5]),packbf(f[6],f[7]));
}

// ---- fp8 e4m3 (OCP, gfx950 HW cvt) helpers ----
__device__ __forceinline__ unsigned pack4_fp8(float a, float b, float c, float d) {
    int w = 0;
    w = __builtin_amdgcn_cvt_pk_fp8_f32(a, b, w, false);
    w = __builtin_amdgcn_cvt_pk_fp8_f32(c, d, w, true);
    return (unsigned)w;
}

// ---- W pack helper: [Wtop;Wbot] (128 x ncols) -> MFMA B-frags ----
__device__ __forceinline__ void pack_one(const float* Wtop, const float* Wbot,
                                         int ncols, uint4* out, int id) {
    int ntiles = ncols >> 4;
    int lane = id & 63;
    int nt = (id >> 6) % ntiles;
    int kt = id / (64 * ntiles);
    int n = nt * 16 + (lane & 15);
    int k0 = kt * 32 + (lane >> 4) * 8;
    const float* src = (k0 < 64) ? (Wtop + k0 * ncols + n) : (Wbot + (k0 - 64) * ncols + n);
    unsigned r[4];
#pragma unroll
    for (int p = 0; p < 4; p++)
        r[p] = packbf(src[(2 * p) * ncols], src[(2 * p + 1) * ncols]);
    out[id] = make_uint4(r[0], r[1], r[2], r[3]);
}

// ---------------- K1: edge bucket-sort (LDS counting sort) + x->bf16 + W packs --
__global__ __launch_bounds__(256) void k1_bucket_conv_pack(
        const int* __restrict__ row, const int* __restrict__ col,
        int* __restrict__ btail, int2* __restrict__ bucketArr,
        const float4* __restrict__ xin, uint4* __restrict__ xbf,
        const float* __restrict__ Wd, const float* __restrict__ Wh1,
        const float* __restrict__ Whd, const float* __restrict__ Wh2,
        uint4* __restrict__ Wfrag1, uint4* __restrict__ Wfrag2) {
    int b = blockIdx.x, tid = threadIdx.x;
    if (b < ABLK) {
        __shared__ int2 buf[EPB];         // 16 KB staging
        __shared__ int cnt[256];
        __shared__ int offs[256];
        __shared__ int gb[256];
        int base = b * EPB;
        int n = E - base; if (n > EPB) n = EPB;
        int r[8], c[8], p[8];
        cnt[tid] = 0;
        __syncthreads();
#pragma unroll
        for (int j = 0; j < 8; j++) {
            int e = base + j * 256 + tid;
            if (e < base + n) {
                r[j] = row[e]; c[j] = col[e];
                p[j] = atomicAdd(&cnt[r[j] >> 8], 1);
            } else r[j] = -1;
        }
        __syncthreads();
        offs[tid] = cnt[tid];
        __syncthreads();
        for (int o = 1; o < 256; o <<= 1) {
            int u = (tid >= o) ? offs[tid - o] : 0;
            __syncthreads();
            offs[tid] += u;
            __syncthreads();
        }
        int excl = offs[tid] - cnt[tid];
        __syncthreads();
        offs[tid] = excl;
        if (tid < NB && cnt[tid] > 0) gb[tid] = atomicAdd(&btail[tid], cnt[tid]);
        __syncthreads();
#pragma unroll
        for (int j = 0; j < 8; j++)
            if (r[j] >= 0) buf[offs[r[j] >> 8] + p[j]] = make_int2(r[j], c[j]);
        __syncthreads();
        for (int i = tid; i < n; i += 256) {
            int2 eg = buf[i];
            int bb = eg.x >> 8;
            int pos = gb[bb] + (i - offs[bb]);
            if (pos < BCAP) bucketArr[(size_t)bb * BCAP + pos] = eg;
        }
    } else if (b < ABLK + CONV_BLOCKS) {
        int i = (b - ABLK) * 256 + tid;
        if (i < (int)(N64 / 8)) {
            float4 a = xin[2 * i], c = xin[2 * i + 1];
            uint4 o;
            o.x = packbf(a.x, a.y); o.y = packbf(a.z, a.w);
            o.z = packbf(c.x, c.y); o.w = packbf(c.z, c.w);
            xbf[i] = o;
        }
    } else if (b < ABLK + CONV_BLOCKS + 4) {
        int id = (b - ABLK - CONV_BLOCKS) * 256 + tid;
        if (id < 1024) pack_one(Wd, Wh1, 64, Wfrag1, id);
    } else {
        int id = (b - ABLK - CONV_BLOCKS - 4) * 256 + tid;
        if (id < 512) pack_one(Whd, Wh2, 32, Wfrag2, id);
    }
}

// ---------------- K_ELL fused: bucket -> ELL(ushort) + deg/dinv/pad/xu(fp8) ----
// Blocks [0,NB): one per bucket. LDS row counters -> ELL; per-row deg, dinv,
// ELL pad-to-8 (col N -> zero row), xu = fp8(dinv .* x) (3.2 MB: fits per-XCD
// L2 for the spmm gather). Block NB: coeffs/kmax + zero pad rows.
__global__ __launch_bounds__(256) void k_ell_fused(
        const int2* __restrict__ bucketArr, const int* __restrict__ btail,
        unsigned short* __restrict__ ell, int* __restrict__ deg,
        const float* __restrict__ x, float* __restrict__ dinv,
        unsigned char* __restrict__ xu, unsigned char* __restrict__ Uarr,
        unsigned char* __restrict__ hidu, int nslots,
        const float* __restrict__ tptr, float* __restrict__ coeffs,
        int* __restrict__ kmaxp) {
    int b = blockIdx.x, tid = threadIdx.x;
    if (b < NB) {
        __shared__ int rcnt[256];
        __shared__ float sdr[256];
        rcnt[tid] = 0;
        __syncthreads();
        int cnt = btail[b]; if (cnt > BCAP) cnt = BCAP;
        const int2* src = bucketArr + (size_t)b * BCAP;
        for (int i = tid; i < cnt; i += 256) {
            int2 eg = src[i];
            int s = atomicAdd(&rcnt[eg.x & 255], 1);
            if (s < 64) ell[(size_t)eg.x * 64 + s] = (unsigned short)eg.y;
        }
        __syncthreads();
        int r0 = b << 8;
        int rr = r0 + tid;
        int dc = rcnt[tid];
        int d = dc > 64 ? 64 : dc;
        float dr = (d > 0) ? rsqrtf((float)d) : 0.f;
        sdr[tid] = dr;
        if (rr < N) {
            deg[rr] = dc;
            dinv[rr] = dr;
            int dpad = (d + 7) & ~7;
            for (int j = d; j < dpad; j++) ell[(size_t)rr * 64 + j] = (unsigned short)N;
        }
        __syncthreads();
        for (int u = tid; u < 1024; u += 256) {      // 256 rows x 4 uint4 (16 fp8 each)
            int lr = u >> 2, sub = u & 3;
            int r = r0 + lr;
            if (r < N) {
                float drr = sdr[lr];
                const float* xp = x + (size_t)r * 64 + sub * 16;
                float4 a = *(const float4*)xp;
                float4 c = *(const float4*)(xp + 4);
                float4 e = *(const float4*)(xp + 8);
                float4 g = *(const float4*)(xp + 12);
                uint4 o;
                o.x = pack4_fp8(drr*a.x, drr*a.y, drr*a.z, drr*a.w);
                o.y = pack4_fp8(drr*c.x, drr*c.y, drr*c.z, drr*c.w);
                o.z = pack4_fp8(drr*e.x, drr*e.y, drr*e.z, drr*e.w);
                o.w = pack4_fp8(drr*g.x, drr*g.y, drr*g.z, drr*g.w);
                ((uint4*)xu)[(size_t)r * 4 + sub] = o;
            }
        }
    } else {
        // coeffs + kmax (bf16-ulp cutoff) + zero pad rows (fp8: 4 uint4 each)
        __shared__ float sc[KCHEB];
        int v = tid;
        if (v < KCHEB) {
            float tt = tptr[0];
            float lt = logf(0.5f * tt);
            float s = 0.f;
            for (int m = 0; m < BT; m++) {
                float lg = lgammaf((float)m + 1.0f) + lgammaf((float)(m + v) + 1.0f);
                s += expf((2.0f * m + (float)v) * lt - lg);
            }
            float c;
            if (v == 0) c = s;
            else c = ((v & 1) == 0) ? 2.0f * s : -2.0f * s;
            coeffs[v] = c;
            sc[v] = c;
        }
        __syncthreads();
        if (v == 0) {
            float c0 = fabsf(sc[0]);
            int kmax = 1;
            for (int k = 1; k < KCHEB; k++)
                if (fabsf(sc[k]) >= 0.00390625f * c0) kmax = k;   // bf16 ulp cutoff
            kmaxp[0] = kmax;
        }
        int total = (nslots + 2) * 4;
        if (tid < total) {
            int which = tid >> 2, q = tid & 3;
            uint4* dst;
            if (which == 0)           dst = (uint4*)(xu + (size_t)N * 64);
            else if (which <= nslots) dst = (uint4*)(Uarr + (size_t)(which - 1) * UROWB + (size_t)N * 64);
            else                      dst = (uint4*)(hidu + (size_t)N * 64);
            dst[q] = make_uint4(0, 0, 0, 0);
        }
    }
}

// ---------------- persistent SpMM phase (fp8 gather, ushort ELL) ---------------
// Gather source u is fp8 (3.2 MB -> resident in each 4 MiB per-XCD L2; the
// 6.4 MB bf16 source missed ~40%). HW v_cvt_pk_f32_fp8 decode keeps the
// latency-bound loop VALU-light. T output stays bf16 (recurrence + matmul).
// Grid 1024 = 4 blocks/CU (R14: 8/CU thrashes L2). Spin barrier between LIVE
// steps only; never runs at kmax==1.
__global__ __launch_bounds__(256, 4) void spmm_phase(
        const int* __restrict__ deg, const unsigned short* __restrict__ ell,
        const unsigned char* __restrict__ baseu, const unsigned short* __restrict__ baseT,
        unsigned short* __restrict__ Tarr, unsigned char* __restrict__ Uarr,
        int nslots, const float* __restrict__ dinv,
        const int* __restrict__ kmaxp, int* __restrict__ barcnt) {
    int tid = threadIdx.x;
    int lane = tid & 63;
    int lane8 = lane & 7;
    int gbase = lane & 56;
    int h = (lane >> 3) & 1;
    int myoff8 = lane8 * 8;
    int kmax = kmaxp[0]; if (kmax > KCHEB - 1) kmax = KCHEB - 1;
    for (int k = 1; k <= kmax; k++) {
        const unsigned char* uin = (k == 1) ? baseu
                                  : Uarr + (size_t)((k - 2) % nslots) * UROWB;
        const uint4* tkm2 = (const uint4*)((k <= 2) ? baseT
                                  : Tarr + (size_t)((k - 3) % nslots) * N64);
        uint4* Tout = (uint4*)(Tarr + (size_t)((k - 1) % nslots) * N64);
        uint2* Uout = (uint2*)(Uarr + (size_t)((k - 1) % nslots) * UROWB);
        const char* vbase = (const char*)uin;
        for (int rb = blockIdx.x; rb < NGROUP; rb += PHASE_GRID) {
            int r = rb * 16 + (tid >> 6) * 4 + (lane >> 4);
            int d = deg[r]; if (d > 64) d = 64;
            int dpad = (d + 7) & ~7;
            const unsigned short* erow = ell + (size_t)r * 64;
            float a0=0,a1=0,a2=0,a3=0,a4=0,a5=0,a6=0,a7=0;
            for (int j0 = h * 8; j0 < dpad; j0 += 16) {
                int myoff = ((int)erow[j0 + lane8]) << 6;   // pads -> row N (zeros)
#pragma unroll
                for (int i = 0; i < 8; i++) {
                    int off = __shfl(myoff, gbase + i, 64);
                    uint2 v = *(const uint2*)(vbase + off + myoff8);
                    f32x2 p0 = __builtin_amdgcn_cvt_pk_f32_fp8((int)v.x, false);
                    f32x2 p1 = __builtin_amdgcn_cvt_pk_f32_fp8((int)v.x, true);
                    f32x2 p2 = __builtin_amdgcn_cvt_pk_f32_fp8((int)v.y, false);
                    f32x2 p3 = __builtin_amdgcn_cvt_pk_f32_fp8((int)v.y, true);
                    a0 += p0.x; a1 += p0.y; a2 += p1.x; a3 += p1.y;
                    a4 += p2.x; a5 += p2.y; a6 += p3.x; a7 += p3.y;
                }
            }
            a0 += __shfl_xor(a0, 8, 64);
            a1 += __shfl_xor(a1, 8, 64);
            a2 += __shfl_xor(a2, 8, 64);
            a3 += __shfl_xor(a3, 8, 64);
            a4 += __shfl_xor(a4, 8, 64);
            a5 += __shfl_xor(a5, 8, 64);
            a6 += __shfl_xor(a6, 8, 64);
            a7 += __shfl_xor(a7, 8, 64);
            if (h == 0) {
                float dr = dinv[r];
                float ndr = -dr;
                float s0=ndr*a0, s1=ndr*a1, s2=ndr*a2, s3=ndr*a3;
                float s4=ndr*a4, s5=ndr*a5, s6=ndr*a6, s7=ndr*a7;
                int idx = r * 8 + lane8;
                if (k >= 2) {
                    uint4 tm = tkm2[idx];
                    s0 = 2.f*s0 - bf2f(tm.x & 0xFFFFu);
                    s1 = 2.f*s1 - bf2f(tm.x >> 16);
                    s2 = 2.f*s2 - bf2f(tm.y & 0xFFFFu);
                    s3 = 2.f*s3 - bf2f(tm.y >> 16);
                    s4 = 2.f*s4 - bf2f(tm.z & 0xFFFFu);
                    s5 = 2.f*s5 - bf2f(tm.z >> 16);
                    s6 = 2.f*s6 - bf2f(tm.w & 0xFFFFu);
                    s7 = 2.f*s7 - bf2f(tm.w >> 16);
                }
                float t8[8] = {s0,s1,s2,s3,s4,s5,s6,s7};
                Tout[idx] = pack8(t8);
                uint2 uo;
                uo.x = pack4_fp8(dr*s0, dr*s1, dr*s2, dr*s3);
                uo.y = pack4_fp8(dr*s4, dr*s5, dr*s6, dr*s7);
                Uout[idx] = uo;
            }
        }
        if (k < kmax) {
            __threadfence();
            __syncthreads();
            if (tid == 0) {
                __hip_atomic_fetch_add(barcnt, 1, __ATOMIC_ACQ_REL, __HIP_MEMORY_SCOPE_AGENT);
                int target = PHASE_GRID * k;
                while (__hip_atomic_load(barcnt, __ATOMIC_ACQUIRE, __HIP_MEMORY_SCOPE_AGENT) < target)
                    __builtin_amdgcn_s_sleep(8);
            }
            __syncthreads();
        }
    }
}

// ---------------- MFMA matmul: hidden = relu([base|heat] @ Bfrag), 64 cols ------
// Also emits hidu = fp8(dinv .* hidden) as phase-2's pre-scaled gather source.
__global__ __launch_bounds__(256) void matmul_hidden(
        const unsigned short* __restrict__ basebf, const unsigned short* __restrict__ Tarr,
        int nslots, const float* __restrict__ coeffs, const int* __restrict__ kmaxp,
        const uint4* __restrict__ Wfrag, unsigned short* __restrict__ hidbf,
        const float* __restrict__ dinv, unsigned char* __restrict__ hidu) {
    __shared__ __align__(16) unsigned short At[64][136];   // pad 8 -> row stride 272B
    int tid = threadIdx.x;
    int row0 = blockIdx.x * 64;
    int kmax = kmaxp[0]; if (kmax > KCHEB - 1) kmax = KCHEB - 1;
    float c0 = coeffs[0];
    for (int u = tid; u < 1024; u += 256) {
        int rr = u >> 4, seg = u & 15;
        int r = row0 + rr;
        uint4 val = make_uint4(0, 0, 0, 0);
        int col;
        if (seg < 8) {
            col = seg * 8;
            if (r < N) val = *(const uint4*)(basebf + (size_t)r * 64 + seg * 8);
        } else {
            int s = seg - 8;
            col = 64 + s * 8;
            if (r < N) {
                uint4 xv = *(const uint4*)(basebf + (size_t)r * 64 + s * 8);
                float h[8], f[8];
                unpack8(xv, f);
#pragma unroll
                for (int q = 0; q < 8; q++) h[q] = c0 * f[q];
                for (int j = 1; j <= kmax; j++) {
                    const unsigned short* Tj = Tarr + (size_t)((j - 1) % nslots) * N64;
                    uint4 tv = *(const uint4*)(Tj + (size_t)r * 64 + s * 8);
                    float g[8];
                    unpack8(tv, g);
                    float cj = coeffs[j];
#pragma unroll
                    for (int q = 0; q < 8; q++) h[q] = fmaf(cj, g[q], h[q]);
                }
                val = pack8(h);
            }
        }
        *(uint4*)&At[rr][col] = val;
    }
    __syncthreads();
    int wv = tid >> 6, lane = tid & 63;
    int m0 = wv * 16;
    short8 afr[4];
#pragma unroll
    for (int kt = 0; kt < 4; kt++)
        afr[kt] = *(const short8*)&At[m0 + (lane & 15)][kt * 32 + (lane >> 4) * 8];
    f32x4 acc[4];
#pragma unroll
    for (int nt = 0; nt < 4; nt++) acc[nt] = (f32x4){0.f, 0.f, 0.f, 0.f};
#pragma unroll
    for (int nt = 0; nt < 4; nt++) {
#pragma unroll
        for (int kt = 0; kt < 4; kt++) {
            short8 bfr = *(const short8*)&Wfrag[kt * 256 + nt * 64 + lane];
            acc[nt] = __builtin_amdgcn_mfma_f32_16x16x32_bf16(afr[kt], bfr, acc[nt], 0, 0, 0);
        }
    }
    float drow[4];
#pragma unroll
    for (int i = 0; i < 4; i++) {
        int r = row0 + m0 + (lane >> 4) * 4 + i;
        drow[i] = (r < N) ? dinv[r] : 0.f;
    }
#pragma unroll
    for (int nt = 0; nt < 4; nt++) {
#pragma unroll
        for (int i = 0; i < 4; i++) {
            int r = row0 + m0 + (lane >> 4) * 4 + i;
            if (r < N) {
                float hv = fmaxf(acc[nt][i], 0.f);
                size_t o = (size_t)r * 64 + nt * 16 + (lane & 15);
                hidbf[o] = (unsigned short)f2bf(hv);
                int w = __builtin_amdgcn_cvt_pk_fp8_f32(drow[i] * hv, 0.f, 0, false);
                hidu[o] = (unsigned char)(w & 0xFF);
            }
        }
    }
}

// ---------------- MFMA matmul + log_softmax: out = lsm([hid|heat2] @ Bfrag) ----
__global__ __launch_bounds__(256) void matmul_out(
        const unsigned short* __restrict__ basebf, const unsigned short* __restrict__ Tarr,
        int nslots, const float* __restrict__ coeffs, const int* __restrict__ kmaxp,
        const uint4* __restrict__ Wfrag, float* __restrict__ out) {
    __shared__ __align__(16) unsigned short At[64][136];
    int tid = threadIdx.x;
    int row0 = blockIdx.x * 64;
    int kmax = kmaxp[0]; if (kmax > KCHEB - 1) kmax = KCHEB - 1;
    float c0 = coeffs[0];
    for (int u = tid; u < 1024; u += 256) {
        int rr = u >> 4, seg = u & 15;
        int r = row0 + rr;
        uint4 val = make_uint4(0, 0, 0, 0);
        int col;
        if (seg < 8) {
            col = seg * 8;
            if (r < N) val = *(const uint4*)(basebf + (size_t)r * 64 + seg * 8);
        } else {
            int s = seg - 8;
            col = 64 + s * 8;
            if (r < N) {
                uint4 xv = *(const uint4*)(basebf + (size_t)r * 64 + s * 8);
                float h[8], f[8];
                unpack8(xv, f);
#pragma unroll
                for (int q = 0; q < 8; q++) h[q] = c0 * f[q];
                for (int j = 1; j <= kmax; j++) {
                    const unsigned short* Tj = Tarr + (size_t)((j - 1) % nslots) * N64;
                    uint4 tv = *(const uint4*)(Tj + (size_t)r * 64 + s * 8);
                    float g[8];
                    unpack8(tv, g);
                    float cj = coeffs[j];
#pragma unroll
                    for (int q = 0; q < 8; q++) h[q] = fmaf(cj, g[q], h[q]);
                }
                val = pack8(h);
            }
        }
        *(uint4*)&At[rr][col] = val;
    }
    __syncthreads();
    int wv = tid >> 6, lane = tid & 63;
    int m0 = wv * 16;
    short8 afr[4];
#pragma unroll
    for (int kt = 0; kt < 4; kt++)
        afr[kt] = *(const short8*)&At[m0 + (lane & 15)][kt * 32 + (lane >> 4) * 8];
    f32x4 acc[2];
    acc[0] = (f32x4){0.f, 0.f, 0.f, 0.f};
    acc[1] = (f32x4){0.f, 0.f, 0.f, 0.f};
#pragma unroll
    for (int nt = 0; nt < 2; nt++) {
#pragma unroll
        for (int kt = 0; kt < 4; kt++) {
            short8 bfr = *(const short8*)&Wfrag[kt * 128 + nt * 64 + lane];
            acc[nt] = __builtin_amdgcn_mfma_f32_16x16x32_bf16(afr[kt], bfr, acc[nt], 0, 0, 0);
        }
    }
#pragma unroll
    for (int i = 0; i < 4; i++) {
        float f0 = acc[0][i], f1 = acc[1][i];
        float m = fmaxf(f0, f1);
#pragma unroll
        for (int o = 1; o < 16; o <<= 1) m = fmaxf(m, __shfl_xor(m, o, 64));
        float s = expf(f0 - m) + expf(f1 - m);
#pragma unroll
        for (int o = 1; o < 16; o <<= 1) s += __shfl_xor(s, o, 64);
        float ls = m + logf(s);
        int r = row0 + m0 + (lane >> 4) * 4 + i;
        if (r < N) {
            out[(size_t)r * 32 + (lane & 15)] = f0 - ls;
            out[(size_t)r * 32 + 16 + (lane & 15)] = f1 - ls;
        }
    }
}

extern "C" void kernel_launch(void* const* d_in, const int* in_sizes, int n_in,
                              void* d_out, int out_size, void* d_ws, size_t ws_size,
                              hipStream_t stream) {
    const float* x   = (const float*)d_in[0];
    const int*   ei  = (const int*)d_in[1];
    const float* Wd  = (const float*)d_in[2];
    const float* Wh1 = (const float*)d_in[3];
    const float* Whd = (const float*)d_in[4];
    const float* Wh2 = (const float*)d_in[5];
    const float* tp  = (const float*)d_in[6];
    const int* row = ei;
    const int* col = ei + E;

    size_t off = 0;
    auto alloc = [&](size_t bytes) -> void* {
        void* p = (char*)d_ws + off;
        off += (bytes + 255) & ~(size_t)255;
        return p;
    };
    int*   btail  = (int*)alloc((size_t)512 * 4);          // [0,NB) tails; [256],[257] barrier counters
    int*   bar1   = btail + 256;
    int*   bar2   = btail + 257;
    int*   deg    = (int*)alloc((size_t)N * 4);
    float* dinv   = (float*)alloc((size_t)N * 4);
    float* coeffs = (float*)alloc(KCHEB * 4);
    int*   kmaxp  = (int*)alloc(4);
    unsigned short* ell = (unsigned short*)alloc((size_t)N * 64 * 2);   // ushort cols
    int2*  bucketArr = (int2*)alloc((size_t)NB * BCAP * 8);   // 8.0 MB
    unsigned short* xbf   = (unsigned short*)alloc(N64 * 2);
    unsigned char*  xu    = (unsigned char*)alloc(UROWB);     // fp8
    unsigned short* hidbf = (unsigned short*)alloc(N64 * 2);
    unsigned char*  hidu  = (unsigned char*)alloc(UROWB);     // fp8
    uint4* Wfrag1 = (uint4*)alloc(1024 * 16);
    uint4* Wfrag2 = (uint4*)alloc(512 * 16);
    size_t per_slot = N64 * 2 + UROWB + 512;
    int nslots = (int)((ws_size - off) / per_slot);
    if (nslots > KCHEB - 1) nslots = KCHEB - 1;
    if (nslots < 3) nslots = 3;    // barrier path slot-aliasing requires >=3
    unsigned short* Tarr = (unsigned short*)alloc((size_t)nslots * N64 * 2);
    unsigned char*  Uarr = (unsigned char*)alloc((size_t)nslots * UROWB);

    hipMemsetAsync(btail, 0, (size_t)512 * 4, stream);

    k1_bucket_conv_pack<<<ABLK + CONV_BLOCKS + 6, 256, 0, stream>>>(
        row, col, btail, bucketArr, (const float4*)x, (uint4*)xbf,
        Wd, Wh1, Whd, Wh2, Wfrag1, Wfrag2);
    k_ell_fused<<<NB + 1, 256, 0, stream>>>(
        bucketArr, btail, ell, deg, x, dinv, xu, Uarr, hidu, nslots, tp, coeffs, kmaxp);

    const int mm_grid = (N + 63) / 64;

    // ---- heat phase 1 (persistent, normal launch, internal k-loop) ----
    spmm_phase<<<PHASE_GRID, 256, 0, stream>>>(deg, ell, xu, xbf,
                                               Tarr, Uarr, nslots, dinv, kmaxp, bar1);
    matmul_hidden<<<mm_grid, 256, 0, stream>>>(xbf, Tarr, nslots, coeffs, kmaxp,
                                               Wfrag1, hidbf, dinv, hidu);

    // ---- heat phase 2 ----
    spmm_phase<<<PHASE_GRID, 256, 0, stream>>>(deg, ell, hidu, hidbf,
                                               Tarr, Uarr, nslots, dinv, kmaxp, bar2);
    matmul_out<<<mm_grid, 256, 0, stream>>>(hidbf, Tarr, nslots, coeffs, kmaxp,
                                            Wfrag2, (float*)d_out);
}